// Round 13
// baseline (47.595 us; speedup 1.0000x reference)
//
#include <hip/hip_runtime.h>

#define NROWS 8192
#define DIM 128
#define NBLK 1040  // 4160 rect tiles (64M x 128N, nj >= mi>>1), 4 per block

typedef _Float16 f16x8 __attribute__((ext_vector_type(8)));
typedef _Float16 f16x2 __attribute__((ext_vector_type(2)));
typedef float f32x16 __attribute__((ext_vector_type(16)));

#define L2E 1.4426950408889634f  // log2(e)

// ---------------------------------------------------------------------------
// Kernel 1: per-row L2 normalize (fp32, as reference). Unchanged (verified).
// ---------------------------------------------------------------------------
__global__ __launch_bounds__(1024) void fmicl_normalize(
    const float* __restrict__ z1, const float* __restrict__ z2,
    _Float16* __restrict__ zh, float* __restrict__ sposB) {
  const int wid = threadIdx.x >> 6;
  const int lane = threadIdx.x & 63;
  const int row = blockIdx.x * 16 + wid;
  const float2 a = ((const float2*)(z1 + (size_t)row * DIM))[lane];
  const float2 b = ((const float2*)(z2 + (size_t)row * DIM))[lane];
  float s1 = a.x * a.x + a.y * a.y;
  float s2 = b.x * b.x + b.y * b.y;
#pragma unroll
  for (int off = 32; off; off >>= 1) {
    s1 += __shfl_xor(s1, off);
    s2 += __shfl_xor(s2, off);
  }
  const float inv1 = 1.0f / fmaxf(sqrtf(s1), 1e-12f);
  const float inv2 = 1.0f / fmaxf(sqrtf(s2), 1e-12f);
  const float n1x = a.x * inv1, n1y = a.y * inv1;
  const float n2x = b.x * inv2, n2y = b.y * inv2;
  const float dx = n1x - n2x, dy = n1y - n2y;
  float dp = dx * dx + dy * dy;
#pragma unroll
  for (int off = 32; off; off >>= 1) dp += __shfl_xor(dp, off);
  f16x2 h;
  h.x = (_Float16)n1x;
  h.y = (_Float16)n1y;
  *(f16x2*)(zh + (size_t)row * DIM + 2 * lane) = h;
  __shared__ float sposL[16];
  if (lane == 0)
    sposL[wid] = logf(expf(-0.5f * dp) + 1e-8f) + 1.0f;  // f'(g_pos)
  __syncthreads();
  if (threadIdx.x == 0) {
    float s = 0.0f;
#pragma unroll
    for (int k = 0; k < 16; ++k) s += sposL[k];
    sposB[blockIdx.x] = s;
  }
}

// tiles before band mi:  C(mi) = 64*mi - s(mi),  s = sum_{m<mi} (m>>1)
__device__ __forceinline__ int cfun(int mi) {
  const int h = mi >> 1;
  return 64 * mi - (h * h - ((mi & 1) ? 0 : h));
}

// Load 32 rows' MFMA fragments (rows r0+l31, granules 2ks+lhi) into regs.
__device__ __forceinline__ void loadRows(const _Float16* __restrict__ zh,
                                         int r0, int l31, int lhi, uint4* v) {
  const uint4* p = (const uint4*)(zh + (size_t)(r0 + l31) * DIM);
#pragma unroll
  for (int ks = 0; ks < 8; ++ks) v[ks] = p[2 * ks + lhi];
}

// ---------------------------------------------------------------------------
// Kernel 2: LDS-free pairwise. zh (2 MB) is fully L2-resident -> staging it
// through LDS was pure overhead (guide common-mistake #7 / m169). Per wave:
// A (64 rows, 2 chains) held in regs across the 4-tile chunk; B fragments
// (32-col slice) loaded straight global->reg per tile with the same per-lane
// pattern as A; compiler emits fine-grained vmcnt waits and interleaves
// loads with the 16-MFMA chain. No LDS, no barriers, no manual vmcnt ->
// free-running waves, ~3 waves/SIMD (no LDS occupancy cap).
// 1040 blocks x 256 threads (4 waves; wave nw owns cols nw*32..+32).
// Block c owns 4 consecutive tiles of the flat band-major list
// {(mi,nj): nj >= mi>>1} (4160 = 4*1040, perfectly balanced).
// Sum = strict-upper g only (per-element j>i mask on crossing tiles
// nj==mi>>1); reduce multiplies by 2. Epilogue:
// g = exp2(fma(log2e,dot,-log2e)) == exp(-d2/2) for unit rows.
// XCD swizzle (bid&7)*130 + bid>>3 (bijective). No atomics.
// ---------------------------------------------------------------------------
__global__ __launch_bounds__(256, 3) void fmicl_pairwise(
    const _Float16* __restrict__ zh, float* __restrict__ pairP) {
  __shared__ float wsum[4];

  const int tid = threadIdx.x;
  const int lane = tid & 63;
  const int nw = tid >> 6;  // wave id == N-slice id (cols nw*32..+32)
  const int l31 = lane & 31;
  const int lhi = lane >> 5;

  // XCD-chunked swizzle (1040 = 8*130, bijective)
  const int cid = (blockIdx.x & 7) * 130 + (blockIdx.x >> 3);
  const int base = cid * 4;

  // ---- decode base -> (mi, nj): estimate from 64m - m^2/4, then correct ----
  int mi;
  {
    const float arg = fmaxf(0.0f, 4096.0f - (float)base);
    mi = (int)(2.0f * (64.0f - sqrtf(arg)));
    mi = mi < 0 ? 0 : (mi > 127 ? 127 : mi);
    while (mi > 0 && cfun(mi) > base) --mi;
    while (mi < 127 && cfun(mi + 1) <= base) ++mi;
  }
  int nj = (mi >> 1) + (base - cfun(mi));

  uint4 a0[8], a1[8];
  loadRows(zh, (mi << 6), l31, lhi, a0);
  loadRows(zh, (mi << 6) + 32, l31, lhi, a1);

  float gsum = 0.0f;
#pragma unroll 1
  for (int t = 0; t < 4; ++t) {
    // ---- B fragments straight from global (L2-resident) ----
    uint4 vb[8];
    loadRows(zh, 128 * nj + 32 * nw, l31, lhi, vb);

    f32x16 acc0 = {}, acc1 = {};
#pragma unroll
    for (int ks = 0; ks < 8; ++ks) {
      const f16x8 bf = __builtin_bit_cast(f16x8, vb[ks]);
      acc0 = __builtin_amdgcn_mfma_f32_32x32x16_f16(
          __builtin_bit_cast(f16x8, a0[ks]), bf, acc0, 0, 0, 0);
      acc1 = __builtin_amdgcn_mfma_f32_32x32x16_f16(
          __builtin_bit_cast(f16x8, a1[ks]), bf, acc1, 0, 0, 0);
    }

    // ---- epilogue: strict-upper only; crossing tiles mask per element ----
    // C/D layout (32x32): col=lane&31, row=(reg&3)+8*(reg>>2)+4*(lane>>5)
    const int jj = 128 * nj + 32 * nw + l31;
    float tsum = 0.0f;
    if (nj == (mi >> 1)) {  // diagonal-crossing tile (block-uniform)
      const int ii0 = (mi << 6) + 4 * lhi;
#pragma unroll
      for (int r = 0; r < 16; ++r) {
        const float e0 = __builtin_amdgcn_exp2f(fmaf(L2E, acc0[r], -L2E));
        const float e1 = __builtin_amdgcn_exp2f(fmaf(L2E, acc1[r], -L2E));
        const int mo = (r & 3) + 8 * (r >> 2);
        tsum += (jj > ii0 + mo) ? e0 : 0.0f;
        tsum += (jj > ii0 + 32 + mo) ? e1 : 0.0f;
      }
    } else {  // pure-upper tile: branchless
#pragma unroll
      for (int r = 0; r < 16; ++r) {
        tsum += __builtin_amdgcn_exp2f(fmaf(L2E, acc0[r], -L2E));
        tsum += __builtin_amdgcn_exp2f(fmaf(L2E, acc1[r], -L2E));
      }
    }
    gsum += tsum;

    // ---- advance (band-major flat order); A-reload on band crossing ----
    ++nj;
    if (nj == 64 && t < 3) {
      ++mi;
      nj = mi >> 1;
      loadRows(zh, (mi << 6), l31, lhi, a0);
      loadRows(zh, (mi << 6) + 32, l31, lhi, a1);
    }
  }

  // ---- per-block reduction -> pairP[cid] ----
#pragma unroll
  for (int off = 32; off; off >>= 1) gsum += __shfl_xor(gsum, off);
  if (lane == 0) wsum[nw] = gsum;
  __syncthreads();
  if (tid == 0) pairP[cid] = wsum[0] + wsum[1] + wsum[2] + wsum[3];
}

// ---------------------------------------------------------------------------
// Kernel 3: single-block fused reduce + assemble scalar (deterministic
// fixed-order tree). pairP holds strict-upper sums -> ordered sum = 2x.
// star_neg = g + EPS exactly, so star_mean = 2*negSum/(N(N-1)) + EPS.
// ---------------------------------------------------------------------------
__global__ void fmicl_reduce(const float* __restrict__ pairP,
                             const float* __restrict__ sposB,
                             float* __restrict__ out) {
  const int t = threadIdx.x;  // 1024 threads = 16 waves
  double nsum =
      (double)pairP[t] + ((t < NBLK - 1024) ? (double)pairP[t + 1024] : 0.0);
  double psum = (t < 512) ? (double)sposB[t] : 0.0;
#pragma unroll
  for (int off = 32; off; off >>= 1) {
    nsum += __shfl_xor(nsum, off);
    psum += __shfl_xor(psum, off);
  }
  __shared__ double ls[2][16];
  const int lane = t & 63;
  const int wid = t >> 6;
  if (lane == 0) {
    ls[0][wid] = nsum;
    ls[1][wid] = psum;
  }
  __syncthreads();
  if (t == 0) {
    double nn = 0.0, pp = 0.0;
#pragma unroll
    for (int q = 0; q < 16; ++q) {
      nn += ls[0][q];
      pp += ls[1][q];
    }
    const double pos_mean = pp / (double)NROWS;
    const double star_mean =
        2.0 * nn / ((double)NROWS * (double)(NROWS - 1)) + 1e-8;
    out[0] = (float)(-pos_mean + 1.5 * star_mean);
  }
}

extern "C" void kernel_launch(void* const* d_in, const int* in_sizes, int n_in,
                              void* d_out, int out_size, void* d_ws,
                              size_t ws_size, hipStream_t stream) {
  const float* z1 = (const float*)d_in[0];
  const float* z2 = (const float*)d_in[1];
  float* out = (float*)d_out;
  char* ws = (char*)d_ws;

  // ws layout (every slot rewritten every call; no memset needed):
  //   [0)     pairP float[1040]   (4160 B, pad to 6144)
  //   [6144)  sposB float[512]    (2048 B)
  //   [8192)  zh    f16[8192*128] (2 MiB, 16B-aligned)
  float* pairP = (float*)(ws + 0);
  float* sposB = (float*)(ws + 6144);
  _Float16* zh = (_Float16*)(ws + 8192);

  fmicl_normalize<<<512, 1024, 0, stream>>>(z1, z2, zh, sposB);
  fmicl_pairwise<<<NBLK, 256, 0, stream>>>(zh, pairP);
  fmicl_reduce<<<1, 1024, 0, stream>>>(pairP, sposB, out);
}